// Round 9
// baseline (1241.281 us; speedup 1.0000x reference)
//
#include <hip/hip_runtime.h>

#define N_NODES 100000
#define N_EDGES 3200000
#define F_IN 256
#define H1 64
#define H2 32
#define C_OUT 1000

// ---- workspace layout (4-byte units), total 14,200,448 fl = 56.8 MB ----
#define OFF_PACKED 0          // u64[N]  (cnt<<32 | head+1)
#define OFF_G      200000     // float[32]
#define OFF_DINV   200064     // float[N]
#define OFF_CNT    300160     // int[N]
#define OFF_HEAD   400256     // int[N]
#define OFF_OFS    500352     // int[N+1]
#define OFF_CSR    600448     // int[E]
#define OFF_NODE2  3800448    // int2[E] (8B aligned)
#define OFF_Y1B    10200448   // ushort[N*64]
#define OFF_Y2Q    13400448   // uchar[N*32]

__device__ __forceinline__ unsigned short f2bf(float f) {
    unsigned u = __float_as_uint(f);
    u += 0x7FFFu + ((u >> 16) & 1u);  // RNE
    return (unsigned short)(u >> 16);
}
__device__ __forceinline__ float bf2f(unsigned short s) {
    return __uint_as_float(((unsigned)s) << 16);
}

// fp8 e4m3fn encode, RNE, saturating
__device__ __forceinline__ unsigned char f2fp8(float x) {
    x = fminf(fmaxf(x, -448.0f), 448.0f);
    unsigned u = __float_as_uint(x);
    unsigned s = (u >> 24) & 0x80u;
    unsigned absu = u & 0x7fffffffu;
    float ax = __uint_as_float(absu);
    if (ax < 0.015625f) {
        int q = __float2int_rn(ax * 512.0f);
        return (unsigned char)(s | (unsigned)q);
    }
    int e = (int)(absu >> 23) - 127;
    unsigned man = absu & 0x7fffffu;
    unsigned m3 = man >> 20;
    unsigned rem = man & 0xFFFFFu;
    if (rem > 0x80000u || (rem == 0x80000u && (m3 & 1u))) m3++;
    if (m3 == 8u) { m3 = 0u; e++; }
    if (e > 8) return (unsigned char)(s | 0x7Eu);
    return (unsigned char)(s | ((unsigned)(e + 7) << 3) | m3);
}

__device__ __forceinline__ float fp8lut_val(int t) {
    int ex = (t >> 3) & 15, man = t & 7;
    int base = ex ? (8 + man) : man;
    float v = ldexpf((float)base, (ex ? ex : 1) - 10);
    return (t & 0x80) ? -v : v;
}

// ---------------- init: packed=0, g=0 ----------------
__global__ void k_init(unsigned long long* __restrict__ packed, float* __restrict__ g) {
    int i = blockIdx.x * 256 + threadIdx.x;
    if (i < N_NODES) packed[i] = 0ULL;
    if (blockIdx.x == 0 && threadIdx.x < H2) g[threadIdx.x] = 0.0f;
}

// ---------------- build: ONE u64 CAS per edge maintains (cnt, head) ----------------
__global__ void k_build(const int* __restrict__ src, const int* __restrict__ dst,
                        unsigned long long* __restrict__ packed,
                        int2* __restrict__ node2) {
    int e = blockIdx.x * 256 + threadIdx.x;
    if (e < N_EDGES) {
        int d = dst[e];
        int s = src[e];
        unsigned long long* addr = &packed[d];
        unsigned long long old = *addr;
        for (;;) {
            unsigned long long nv =
                (((old >> 32) + 1ULL) << 32) | (unsigned long long)(unsigned)(e + 1);
            unsigned long long got = atomicCAS(addr, old, nv);
            if (got == old) break;
            old = got;
        }
        node2[e] = make_int2(s, (int)(unsigned)(old & 0xffffffffULL) - 1);  // coalesced
    }
}

// ---------------- extract cnt/head, dinv ----------------
__global__ void k_dinv(const unsigned long long* __restrict__ packed,
                       int* __restrict__ cnt, int* __restrict__ head,
                       float* __restrict__ dinv) {
    int n = blockIdx.x * 256 + threadIdx.x;
    if (n < N_NODES) {
        unsigned long long p = packed[n];
        int cdeg = (int)(p >> 32);
        cnt[n] = cdeg;
        head[n] = (int)(unsigned)(p & 0xffffffffULL) - 1;
        dinv[n] = rsqrtf(1.0f + (float)cdeg);
    }
}

// ---------------- single-block exclusive scan -> ofs ----------------
__global__ __launch_bounds__(1024) void k_scan(const int* __restrict__ cnt,
                                               int* __restrict__ ofs) {
    __shared__ int lds[1024];
    const int t = threadIdx.x;
    const int CH = (N_NODES + 1023) / 1024;  // 98
    int base = t * CH;
    int end = base + CH; if (end > N_NODES) end = N_NODES;
    int s = 0;
    for (int i = base; i < end; i++) s += cnt[i];
    lds[t] = s;
    __syncthreads();
    for (int off = 1; off < 1024; off <<= 1) {
        int v = (t >= off) ? lds[t - off] : 0;
        __syncthreads();
        lds[t] += v;
        __syncthreads();
    }
    int run = lds[t] - s;
    for (int i = base; i < end; i++) {
        ofs[i] = run;
        run += cnt[i];
    }
    if (t == 1023) ofs[N_NODES] = lds[1023];  // == E
}

// ---------------- layer-1 GEMM, 2-node register blocking, bf16 output ----------------
__global__ __launch_bounds__(256) void k_gemm1(const float* __restrict__ x,
                                               const float* __restrict__ W1,
                                               const float* __restrict__ dinv,
                                               unsigned short* __restrict__ y1b) {
    __shared__ float w[F_IN][H1];  // 64 KB
    {
        const float4* Wv = (const float4*)W1;
        float4* wv = (float4*)&w[0][0];
        for (int i = threadIdx.x; i < F_IN * H1 / 4; i += 256) wv[i] = Wv[i];
    }
    __syncthreads();
    int n0 = blockIdx.x * 512 + threadIdx.x;
    int n1 = n0 + 256;
    bool v0 = n0 < N_NODES, v1 = n1 < N_NODES;
    int n0c = v0 ? n0 : 0, n1c = v1 ? n1 : 0;

    float acc0[H1], acc1[H1];
#pragma unroll
    for (int j = 0; j < H1; j++) { acc0[j] = 0.0f; acc1[j] = 0.0f; }

    const float4* xr0 = (const float4*)(x + (size_t)n0c * F_IN);
    const float4* xr1 = (const float4*)(x + (size_t)n1c * F_IN);
#pragma unroll 2
    for (int k0 = 0; k0 < F_IN / 4; k0++) {
        float4 xa = xr0[k0];
        float4 xb = xr1[k0];
#pragma unroll
        for (int d = 0; d < 4; d++) {
            float xv0 = (d == 0 ? xa.x : d == 1 ? xa.y : d == 2 ? xa.z : xa.w);
            float xv1 = (d == 0 ? xb.x : d == 1 ? xb.y : d == 2 ? xb.z : xb.w);
            const float4* wr = (const float4*)&w[k0 * 4 + d][0];
#pragma unroll
            for (int j4 = 0; j4 < H1 / 4; j4++) {
                float4 wq = wr[j4];
                acc0[j4 * 4 + 0] += xv0 * wq.x;
                acc0[j4 * 4 + 1] += xv0 * wq.y;
                acc0[j4 * 4 + 2] += xv0 * wq.z;
                acc0[j4 * 4 + 3] += xv0 * wq.w;
                acc1[j4 * 4 + 0] += xv1 * wq.x;
                acc1[j4 * 4 + 1] += xv1 * wq.y;
                acc1[j4 * 4 + 2] += xv1 * wq.z;
                acc1[j4 * 4 + 3] += xv1 * wq.w;
            }
        }
    }
    if (v0) {
        float dv = dinv[n0];
        unsigned pk[H1 / 2];
#pragma unroll
        for (int j2 = 0; j2 < H1 / 2; j2++) {
            unsigned lo = f2bf(acc0[2 * j2] * dv);
            unsigned hi = f2bf(acc0[2 * j2 + 1] * dv);
            pk[j2] = lo | (hi << 16);
        }
        uint4* o = (uint4*)(y1b + (size_t)n0 * H1);
#pragma unroll
        for (int q = 0; q < H1 / 8; q++)
            o[q] = make_uint4(pk[q * 4], pk[q * 4 + 1], pk[q * 4 + 2], pk[q * 4 + 3]);
    }
    if (v1) {
        float dv = dinv[n1];
        unsigned pk[H1 / 2];
#pragma unroll
        for (int j2 = 0; j2 < H1 / 2; j2++) {
            unsigned lo = f2bf(acc1[2 * j2] * dv);
            unsigned hi = f2bf(acc1[2 * j2 + 1] * dv);
            pk[j2] = lo | (hi << 16);
        }
        uint4* o = (uint4*)(y1b + (size_t)n1 * H1);
#pragma unroll
        for (int q = 0; q < H1 / 8; q++)
            o[q] = make_uint4(pk[q * 4], pk[q * 4 + 1], pk[q * 4 + 2], pk[q * 4 + 3]);
    }
}

// ---------------- fused: chain-gather layer1 + CSR write + ReLU + GEMM2 -> y2 (fp8) ----------------
// block=256 = 4 waves; wave walks TWO chains; lanes 0/1 record srcs into CSR.
__global__ __launch_bounds__(256) void k_agg1_gemm2(const unsigned short* __restrict__ y1b,
                                                    const int* __restrict__ head,
                                                    const int2* __restrict__ node2,
                                                    const int* __restrict__ ofs,
                                                    int* __restrict__ csr,
                                                    const float* __restrict__ dinv,
                                                    const float* __restrict__ b1,
                                                    const float* __restrict__ W2,
                                                    unsigned char* __restrict__ y2q) {
    __shared__ float w2s[H1][H2];  // 8 KB
    __shared__ float hbuf[8][H1];  // 2 KB
    {
        const float4* Wv = (const float4*)W2;
        float4* wv = (float4*)&w2s[0][0];
        for (int i = threadIdx.x; i < H1 * H2 / 4; i += 256) wv[i] = Wv[i];
    }

    const int t = threadIdx.x;
    const int wid = t >> 6;
    const int lane = t & 63;
    const int c = lane;
    const int n0 = blockIdx.x * 8 + wid * 2;
    const int n1 = n0 + 1;

    float a0 = bf2f(y1b[(size_t)n0 * H1 + c]);  // self-loop
    float a1 = bf2f(y1b[(size_t)n1 * H1 + c]);
    int e0 = head[n0], e1 = head[n1];
    const int ofs0 = ofs[n0], ofs1 = ofs[n1];
    int k = 0;
    while (e0 >= 0 && e1 >= 0) {
        int2 v0 = node2[e0];
        int2 v1 = node2[e1];
        if (lane == 0) csr[ofs0 + k] = v0.x;
        if (lane == 1) csr[ofs1 + k] = v1.x;
        a0 += bf2f(y1b[(size_t)v0.x * H1 + c]);
        a1 += bf2f(y1b[(size_t)v1.x * H1 + c]);
        e0 = v0.y; e1 = v1.y; k++;
    }
    int k0 = k, k1 = k;
    while (e0 >= 0) {
        int2 v0 = node2[e0];
        if (lane == 0) csr[ofs0 + k0] = v0.x;
        a0 += bf2f(y1b[(size_t)v0.x * H1 + c]);
        e0 = v0.y; k0++;
    }
    while (e1 >= 0) {
        int2 v1 = node2[e1];
        if (lane == 1) csr[ofs1 + k1] = v1.x;
        a1 += bf2f(y1b[(size_t)v1.x * H1 + c]);
        e1 = v1.y; k1++;
    }
    float h0 = dinv[n0] * a0 + b1[c];
    float h1v = dinv[n1] * a1 + b1[c];
    hbuf[wid * 2 + 0][c] = h0 > 0.0f ? h0 : 0.0f;
    hbuf[wid * 2 + 1][c] = h1v > 0.0f ? h1v : 0.0f;
    __syncthreads();

    // GEMM2: 256 threads = 8 nodes x 32 outputs -> fp8 store
    {
        int w = t >> 5, j = t & 31;
        int n2 = blockIdx.x * 8 + w;
        float dot = 0.0f;
#pragma unroll
        for (int cc = 0; cc < H1; cc++) dot += hbuf[w][cc] * w2s[cc][j];
        y2q[(size_t)n2 * H2 + j] = f2fp8(dinv[n2] * dot);
    }
}

// ---------------- CSR-gather layer2 (fp8 LUT) + ReLU + mean-pool ----------------
// block=256 = 8 half-waves = 8 nodes; index reads are sequential broadcasts.
__global__ __launch_bounds__(256) void k_agg2_pool(const unsigned char* __restrict__ y2q,
                                                   const int* __restrict__ ofs,
                                                   const int* __restrict__ csr,
                                                   const float* __restrict__ dinv,
                                                   const float* __restrict__ b2,
                                                   float* __restrict__ g) {
    __shared__ float lut[256];
    __shared__ float red[256];
    const int t = threadIdx.x;
    lut[t] = fp8lut_val(t);
    __syncthreads();

    const int n = blockIdx.x * 8 + (t >> 5);
    const int c = t & 31;

    float a = lut[y2q[(size_t)n * H2 + c]];  // self-loop
    const int p0 = ofs[n], p1 = ofs[n + 1];
    for (int p = p0; p < p1; p++) {
        int s = csr[p];
        a += lut[y2q[(size_t)s * H2 + c]];
    }
    float hv = dinv[n] * a + b2[c];
    red[t] = hv > 0.0f ? hv : 0.0f;
    __syncthreads();
    if (t < 128) red[t] += red[t + 128];
    __syncthreads();
    if (t < 64) red[t] += red[t + 64];
    __syncthreads();
    if (t < 32) {
        float s = red[t] + red[t + 32];
        atomicAdd(&g[t], s);
    }
}

__global__ void k_fc(const float* __restrict__ g, const float* __restrict__ Wfc,
                     const float* __restrict__ bfc, float* __restrict__ out) {
    int c = blockIdx.x * 256 + threadIdx.x;
    if (c < C_OUT) {
        const float invn = 1.0f / (float)N_NODES;
        float s = bfc[c];
#pragma unroll
        for (int k = 0; k < H2; k++) s += (g[k] * invn) * Wfc[k * C_OUT + c];
        out[c] = s;
    }
}

extern "C" void kernel_launch(void* const* d_in, const int* in_sizes, int n_in,
                              void* d_out, int out_size, void* d_ws, size_t ws_size,
                              hipStream_t stream) {
    const float* x   = (const float*)d_in[0];
    const int* esrc  = (const int*)d_in[1];
    const int* edst  = (const int*)d_in[2];
    const float* W1  = (const float*)d_in[3];
    const float* b1  = (const float*)d_in[4];
    const float* W2  = (const float*)d_in[5];
    const float* b2  = (const float*)d_in[6];
    const float* Wfc = (const float*)d_in[7];
    const float* bfc = (const float*)d_in[8];
    float* out = (float*)d_out;

    float* ws = (float*)d_ws;
    unsigned long long* packed = (unsigned long long*)(ws + OFF_PACKED);
    float* g    = ws + OFF_G;
    float* dinv = ws + OFF_DINV;
    int*   cnt  = (int*)(ws + OFF_CNT);
    int*   head = (int*)(ws + OFF_HEAD);
    int*   ofs  = (int*)(ws + OFF_OFS);
    int*   csr  = (int*)(ws + OFF_CSR);
    int2*  node2 = (int2*)(ws + OFF_NODE2);
    unsigned short* y1b = (unsigned short*)(ws + OFF_Y1B);
    unsigned char*  y2q = (unsigned char*)(ws + OFF_Y2Q);

    const int nb_n = (N_NODES + 255) / 256;  // 391
    const int nb_e = (N_EDGES + 255) / 256;  // 12500

    k_init<<<nb_n, 256, 0, stream>>>(packed, g);
    k_build<<<nb_e, 256, 0, stream>>>(esrc, edst, packed, node2);
    k_dinv<<<nb_n, 256, 0, stream>>>(packed, cnt, head, dinv);
    k_scan<<<1, 1024, 0, stream>>>(cnt, ofs);

    k_gemm1<<<(N_NODES + 511) / 512, 256, 0, stream>>>(x, W1, dinv, y1b);
    k_agg1_gemm2<<<N_NODES / 8, 256, 0, stream>>>(y1b, head, node2, ofs, csr, dinv, b1, W2, y2q);
    k_agg2_pool<<<N_NODES / 8, 256, 0, stream>>>(y2q, ofs, csr, dinv, b2, g);

    k_fc<<<(C_OUT + 255) / 256, 256, 0, stream>>>(g, Wfc, bfc, out);
}

// Round 10
// 1055.929 us; speedup vs baseline: 1.1755x; 1.1755x over previous
//
#include <hip/hip_runtime.h>

#define N_NODES 100000
#define N_EDGES 3200000
#define F_IN 256
#define H1 64
#define H2 32
#define C_OUT 1000

// ---- workspace layout (4-byte units), total 12,400,384 fl = 49.6 MB ----
#define OFF_G      0          // float[32]
#define OFF_DINV   64         // float[N]
#define OFF_CNT    100096     // int[N]
#define OFF_HEAD   200192     // int[N]
#define OFF_OFS    300288     // int[N+1]
#define OFF_CSR    400384     // int[E]
#define OFF_NODE2  3600384    // int2[E] (8B aligned)
#define OFF_Y1Q    10000384   // uchar[N*64] = 1.6M fl
#define OFF_Y2Q    11600384   // uchar[N*32] = 0.8M fl

// fp8 e4m3fn encode, RNE, saturating
__device__ __forceinline__ unsigned char f2fp8(float x) {
    x = fminf(fmaxf(x, -448.0f), 448.0f);
    unsigned u = __float_as_uint(x);
    unsigned s = (u >> 24) & 0x80u;
    unsigned absu = u & 0x7fffffffu;
    float ax = __uint_as_float(absu);
    if (ax < 0.015625f) {
        int q = __float2int_rn(ax * 512.0f);
        return (unsigned char)(s | (unsigned)q);
    }
    int e = (int)(absu >> 23) - 127;
    unsigned man = absu & 0x7fffffu;
    unsigned m3 = man >> 20;
    unsigned rem = man & 0xFFFFFu;
    if (rem > 0x80000u || (rem == 0x80000u && (m3 & 1u))) m3++;
    if (m3 == 8u) { m3 = 0u; e++; }
    if (e > 8) return (unsigned char)(s | 0x7Eu);
    return (unsigned char)(s | ((unsigned)(e + 7) << 3) | m3);
}

__device__ __forceinline__ float fp8lut_val(int t) {
    int ex = (t >> 3) & 15, man = t & 7;
    int base = ex ? (8 + man) : man;
    float v = ldexpf((float)base, (ex ? ex : 1) - 10);
    return (t & 0x80) ? -v : v;
}

// ---------------- init: head=-1, g=0 ----------------
__global__ void k_init(int* __restrict__ head, float* __restrict__ g) {
    int i = blockIdx.x * 256 + threadIdx.x;
    if (i < N_NODES) head[i] = -1;
    if (blockIdx.x == 0 && threadIdx.x < H2) g[threadIdx.x] = 0.0f;
}

// ---------------- build: ONE atomicExch per edge; coalesced int2 write ----------------
__global__ void k_build(const int* __restrict__ src, const int* __restrict__ dst,
                        int* __restrict__ head, int2* __restrict__ node2) {
    int e = blockIdx.x * 256 + threadIdx.x;
    if (e < N_EDGES) {
        int d = dst[e];
        int s = src[e];
        int prev = atomicExch(&head[d], e);
        node2[e] = make_int2(s, prev);
    }
}

// ---------------- degree via chain walk -> cnt, dinv ----------------
__global__ void k_deg(const int* __restrict__ head, const int2* __restrict__ node2,
                      int* __restrict__ cnt, float* __restrict__ dinv) {
    int n = blockIdx.x * 256 + threadIdx.x;
    if (n < N_NODES) {
        int k = 0;
        int e = head[n];
        while (e >= 0) { k++; e = node2[e].y; }
        cnt[n] = k;
        dinv[n] = rsqrtf(1.0f + (float)k);
    }
}

// ---------------- single-block exclusive scan -> ofs ----------------
__global__ __launch_bounds__(1024) void k_scan(const int* __restrict__ cnt,
                                               int* __restrict__ ofs) {
    __shared__ int lds[1024];
    const int t = threadIdx.x;
    const int CH = (N_NODES + 1023) / 1024;  // 98
    int base = t * CH;
    int end = base + CH; if (end > N_NODES) end = N_NODES;
    int s = 0;
    for (int i = base; i < end; i++) s += cnt[i];
    lds[t] = s;
    __syncthreads();
    for (int off = 1; off < 1024; off <<= 1) {
        int v = (t >= off) ? lds[t - off] : 0;
        __syncthreads();
        lds[t] += v;
        __syncthreads();
    }
    int run = lds[t] - s;
    for (int i = base; i < end; i++) {
        ofs[i] = run;
        run += cnt[i];
    }
    if (t == 1023) ofs[N_NODES] = lds[1023];  // == E
}

// ---------------- layer-1 GEMM, 2-node register blocking, fp8 output ----------------
__global__ __launch_bounds__(256) void k_gemm1(const float* __restrict__ x,
                                               const float* __restrict__ W1,
                                               const float* __restrict__ dinv,
                                               unsigned char* __restrict__ y1q) {
    __shared__ float w[F_IN][H1];  // 64 KB
    {
        const float4* Wv = (const float4*)W1;
        float4* wv = (float4*)&w[0][0];
        for (int i = threadIdx.x; i < F_IN * H1 / 4; i += 256) wv[i] = Wv[i];
    }
    __syncthreads();
    int n0 = blockIdx.x * 512 + threadIdx.x;
    int n1 = n0 + 256;
    bool v0 = n0 < N_NODES, v1 = n1 < N_NODES;
    int n0c = v0 ? n0 : 0, n1c = v1 ? n1 : 0;

    float acc0[H1], acc1[H1];
#pragma unroll
    for (int j = 0; j < H1; j++) { acc0[j] = 0.0f; acc1[j] = 0.0f; }

    const float4* xr0 = (const float4*)(x + (size_t)n0c * F_IN);
    const float4* xr1 = (const float4*)(x + (size_t)n1c * F_IN);
#pragma unroll 2
    for (int k0 = 0; k0 < F_IN / 4; k0++) {
        float4 xa = xr0[k0];
        float4 xb = xr1[k0];
#pragma unroll
        for (int d = 0; d < 4; d++) {
            float xv0 = (d == 0 ? xa.x : d == 1 ? xa.y : d == 2 ? xa.z : xa.w);
            float xv1 = (d == 0 ? xb.x : d == 1 ? xb.y : d == 2 ? xb.z : xb.w);
            const float4* wr = (const float4*)&w[k0 * 4 + d][0];
#pragma unroll
            for (int j4 = 0; j4 < H1 / 4; j4++) {
                float4 wq = wr[j4];
                acc0[j4 * 4 + 0] += xv0 * wq.x;
                acc0[j4 * 4 + 1] += xv0 * wq.y;
                acc0[j4 * 4 + 2] += xv0 * wq.z;
                acc0[j4 * 4 + 3] += xv0 * wq.w;
                acc1[j4 * 4 + 0] += xv1 * wq.x;
                acc1[j4 * 4 + 1] += xv1 * wq.y;
                acc1[j4 * 4 + 2] += xv1 * wq.z;
                acc1[j4 * 4 + 3] += xv1 * wq.w;
            }
        }
    }
    if (v0) {
        float dv = dinv[n0];
        unsigned pk[H1 / 4];
#pragma unroll
        for (int q = 0; q < H1 / 4; q++) {
            unsigned b0 = f2fp8(acc0[4 * q + 0] * dv);
            unsigned b1 = f2fp8(acc0[4 * q + 1] * dv);
            unsigned b2 = f2fp8(acc0[4 * q + 2] * dv);
            unsigned b3 = f2fp8(acc0[4 * q + 3] * dv);
            pk[q] = b0 | (b1 << 8) | (b2 << 16) | (b3 << 24);
        }
        uint4* o = (uint4*)(y1q + (size_t)n0 * H1);
#pragma unroll
        for (int q = 0; q < H1 / 16; q++)
            o[q] = make_uint4(pk[q * 4], pk[q * 4 + 1], pk[q * 4 + 2], pk[q * 4 + 3]);
    }
    if (v1) {
        float dv = dinv[n1];
        unsigned pk[H1 / 4];
#pragma unroll
        for (int q = 0; q < H1 / 4; q++) {
            unsigned b0 = f2fp8(acc1[4 * q + 0] * dv);
            unsigned b1 = f2fp8(acc1[4 * q + 1] * dv);
            unsigned b2 = f2fp8(acc1[4 * q + 2] * dv);
            unsigned b3 = f2fp8(acc1[4 * q + 3] * dv);
            pk[q] = b0 | (b1 << 8) | (b2 << 16) | (b3 << 24);
        }
        uint4* o = (uint4*)(y1q + (size_t)n1 * H1);
#pragma unroll
        for (int q = 0; q < H1 / 16; q++)
            o[q] = make_uint4(pk[q * 4], pk[q * 4 + 1], pk[q * 4 + 2], pk[q * 4 + 3]);
    }
}

// ---------------- fused: chain-gather layer1 (fp8 LUT) + CSR write + ReLU + GEMM2 -> y2 (fp8) ----------------
// block=256 = 4 waves; wave walks TWO chains; lanes 0/1 record srcs into CSR.
__global__ __launch_bounds__(256) void k_agg1_gemm2(const unsigned char* __restrict__ y1q,
                                                    const int* __restrict__ head,
                                                    const int2* __restrict__ node2,
                                                    const int* __restrict__ ofs,
                                                    int* __restrict__ csr,
                                                    const float* __restrict__ dinv,
                                                    const float* __restrict__ b1,
                                                    const float* __restrict__ W2,
                                                    unsigned char* __restrict__ y2q) {
    __shared__ float w2s[H1][H2];  // 8 KB
    __shared__ float hbuf[8][H1];  // 2 KB
    __shared__ float lut[256];     // 1 KB
    const int t = threadIdx.x;
    lut[t] = fp8lut_val(t);
    {
        const float4* Wv = (const float4*)W2;
        float4* wv = (float4*)&w2s[0][0];
        for (int i = t; i < H1 * H2 / 4; i += 256) wv[i] = Wv[i];
    }
    __syncthreads();

    const int wid = t >> 6;
    const int lane = t & 63;
    const int c = lane;
    const int n0 = blockIdx.x * 8 + wid * 2;
    const int n1 = n0 + 1;

    float a0 = lut[y1q[(size_t)n0 * H1 + c]];  // self-loop
    float a1 = lut[y1q[(size_t)n1 * H1 + c]];
    int e0 = head[n0], e1 = head[n1];
    const int ofs0 = ofs[n0], ofs1 = ofs[n1];
    int k = 0;
    while (e0 >= 0 && e1 >= 0) {
        int2 v0 = node2[e0];
        int2 v1 = node2[e1];
        if (lane == 0) csr[ofs0 + k] = v0.x;
        if (lane == 1) csr[ofs1 + k] = v1.x;
        a0 += lut[y1q[(size_t)v0.x * H1 + c]];
        a1 += lut[y1q[(size_t)v1.x * H1 + c]];
        e0 = v0.y; e1 = v1.y; k++;
    }
    int k0 = k, k1 = k;
    while (e0 >= 0) {
        int2 v0 = node2[e0];
        if (lane == 0) csr[ofs0 + k0] = v0.x;
        a0 += lut[y1q[(size_t)v0.x * H1 + c]];
        e0 = v0.y; k0++;
    }
    while (e1 >= 0) {
        int2 v1 = node2[e1];
        if (lane == 1) csr[ofs1 + k1] = v1.x;
        a1 += lut[y1q[(size_t)v1.x * H1 + c]];
        e1 = v1.y; k1++;
    }
    float h0 = dinv[n0] * a0 + b1[c];
    float h1v = dinv[n1] * a1 + b1[c];
    hbuf[wid * 2 + 0][c] = h0 > 0.0f ? h0 : 0.0f;
    hbuf[wid * 2 + 1][c] = h1v > 0.0f ? h1v : 0.0f;
    __syncthreads();

    // GEMM2: 256 threads = 8 nodes x 32 outputs -> fp8 store
    {
        int w = t >> 5, j = t & 31;
        int n2 = blockIdx.x * 8 + w;
        float dot = 0.0f;
#pragma unroll
        for (int cc = 0; cc < H1; cc++) dot += hbuf[w][cc] * w2s[cc][j];
        y2q[(size_t)n2 * H2 + j] = f2fp8(dinv[n2] * dot);
    }
}

// ---------------- CSR-gather layer2 (fp8 LUT) + ReLU + mean-pool ----------------
// block=256 = 8 half-waves = 8 nodes; index reads are sequential broadcasts.
__global__ __launch_bounds__(256) void k_agg2_pool(const unsigned char* __restrict__ y2q,
                                                   const int* __restrict__ ofs,
                                                   const int* __restrict__ csr,
                                                   const float* __restrict__ dinv,
                                                   const float* __restrict__ b2,
                                                   float* __restrict__ g) {
    __shared__ float lut[256];
    __shared__ float red[256];
    const int t = threadIdx.x;
    lut[t] = fp8lut_val(t);
    __syncthreads();

    const int n = blockIdx.x * 8 + (t >> 5);
    const int c = t & 31;

    float a = lut[y2q[(size_t)n * H2 + c]];  // self-loop
    const int p0 = ofs[n], p1 = ofs[n + 1];
    for (int p = p0; p < p1; p++) {
        int s = csr[p];
        a += lut[y2q[(size_t)s * H2 + c]];
    }
    float hv = dinv[n] * a + b2[c];
    red[t] = hv > 0.0f ? hv : 0.0f;
    __syncthreads();
    if (t < 128) red[t] += red[t + 128];
    __syncthreads();
    if (t < 64) red[t] += red[t + 64];
    __syncthreads();
    if (t < 32) {
        float s = red[t] + red[t + 32];
        atomicAdd(&g[t], s);
    }
}

__global__ void k_fc(const float* __restrict__ g, const float* __restrict__ Wfc,
                     const float* __restrict__ bfc, float* __restrict__ out) {
    int c = blockIdx.x * 256 + threadIdx.x;
    if (c < C_OUT) {
        const float invn = 1.0f / (float)N_NODES;
        float s = bfc[c];
#pragma unroll
        for (int k = 0; k < H2; k++) s += (g[k] * invn) * Wfc[k * C_OUT + c];
        out[c] = s;
    }
}

extern "C" void kernel_launch(void* const* d_in, const int* in_sizes, int n_in,
                              void* d_out, int out_size, void* d_ws, size_t ws_size,
                              hipStream_t stream) {
    const float* x   = (const float*)d_in[0];
    const int* esrc  = (const int*)d_in[1];
    const int* edst  = (const int*)d_in[2];
    const float* W1  = (const float*)d_in[3];
    const float* b1  = (const float*)d_in[4];
    const float* W2  = (const float*)d_in[5];
    const float* b2  = (const float*)d_in[6];
    const float* Wfc = (const float*)d_in[7];
    const float* bfc = (const float*)d_in[8];
    float* out = (float*)d_out;

    float* ws = (float*)d_ws;
    float* g    = ws + OFF_G;
    float* dinv = ws + OFF_DINV;
    int*   cnt  = (int*)(ws + OFF_CNT);
    int*   head = (int*)(ws + OFF_HEAD);
    int*   ofs  = (int*)(ws + OFF_OFS);
    int*   csr  = (int*)(ws + OFF_CSR);
    int2*  node2 = (int2*)(ws + OFF_NODE2);
    unsigned char* y1q = (unsigned char*)(ws + OFF_Y1Q);
    unsigned char* y2q = (unsigned char*)(ws + OFF_Y2Q);

    const int nb_n = (N_NODES + 255) / 256;  // 391
    const int nb_e = (N_EDGES + 255) / 256;  // 12500

    k_init<<<nb_n, 256, 0, stream>>>(head, g);
    k_build<<<nb_e, 256, 0, stream>>>(esrc, edst, head, node2);
    k_deg<<<nb_n, 256, 0, stream>>>(head, node2, cnt, dinv);
    k_scan<<<1, 1024, 0, stream>>>(cnt, ofs);

    k_gemm1<<<(N_NODES + 511) / 512, 256, 0, stream>>>(x, W1, dinv, y1q);
    k_agg1_gemm2<<<N_NODES / 8, 256, 0, stream>>>(y1q, head, node2, ofs, csr, dinv, b1, W2, y2q);
    k_agg2_pool<<<N_NODES / 8, 256, 0, stream>>>(y2q, ofs, csr, dinv, b2, g);

    k_fc<<<(C_OUT + 255) / 256, 256, 0, stream>>>(g, Wfc, bfc, out);
}

// Round 11
// 1029.101 us; speedup vs baseline: 1.2062x; 1.0261x over previous
//
#include <hip/hip_runtime.h>

#define N_NODES 100000
#define N_EDGES 3200000
#define F_IN 256
#define H1 64
#define H2 32
#define C_OUT 1000

// ---- workspace layout (4-byte units), total 12,400,384 fl = 49.6 MB ----
#define OFF_G      0          // float[32]
#define OFF_DINV   64         // float[N]
#define OFF_CNT    100096     // int[N]
#define OFF_HEAD   200192     // int[N]
#define OFF_OFS    300288     // int[N+1]
#define OFF_CSR    400384     // int[E]
#define OFF_NODE2  3600384    // int2[E] (8B aligned)
#define OFF_Y1Q    10000384   // uchar[N*64]
#define OFF_Y2Q    11600384   // uchar[N*32]

// fp8 e4m3fn encode, RNE, saturating (proven R10)
__device__ __forceinline__ unsigned char f2fp8(float x) {
    x = fminf(fmaxf(x, -448.0f), 448.0f);
    unsigned u = __float_as_uint(x);
    unsigned s = (u >> 24) & 0x80u;
    unsigned absu = u & 0x7fffffffu;
    float ax = __uint_as_float(absu);
    if (ax < 0.015625f) {
        int q = __float2int_rn(ax * 512.0f);
        return (unsigned char)(s | (unsigned)q);
    }
    int e = (int)(absu >> 23) - 127;
    unsigned man = absu & 0x7fffffu;
    unsigned m3 = man >> 20;
    unsigned rem = man & 0xFFFFFu;
    if (rem > 0x80000u || (rem == 0x80000u && (m3 & 1u))) m3++;
    if (m3 == 8u) { m3 = 0u; e++; }
    if (e > 8) return (unsigned char)(s | 0x7Eu);
    return (unsigned char)(s | ((unsigned)(e + 7) << 3) | m3);
}

// fp8 e4m3fn decode, branchless ALU (no LDS LUT -> no bank conflicts)
__device__ __forceinline__ float fp8dec(unsigned b) {
    unsigned ex = (b >> 3) & 15u, man = b & 7u;
    float vn = __uint_as_float(((ex + 120u) << 23) | (man << 20));
    float vs = (float)man * 0.001953125f;  // man * 2^-9
    float v = ex ? vn : vs;
    return (b & 0x80u) ? -v : v;
}

// ---------------- init: head=-1, g=0 ----------------
__global__ void k_init(int* __restrict__ head, float* __restrict__ g) {
    int i = blockIdx.x * 256 + threadIdx.x;
    if (i < N_NODES) head[i] = -1;
    if (blockIdx.x == 0 && threadIdx.x < H2) g[threadIdx.x] = 0.0f;
}

// ---------------- build: ONE atomicExch per edge; coalesced int2 write ----------------
__global__ void k_build(const int* __restrict__ src, const int* __restrict__ dst,
                        int* __restrict__ head, int2* __restrict__ node2) {
    int e = blockIdx.x * 256 + threadIdx.x;
    if (e < N_EDGES) {
        int d = dst[e];
        int s = src[e];
        int prev = atomicExch(&head[d], e);
        node2[e] = make_int2(s, prev);
    }
}

// ---------------- single-block exclusive scan -> ofs ----------------
__global__ __launch_bounds__(1024) void k_scan(const int* __restrict__ cnt,
                                               int* __restrict__ ofs) {
    __shared__ int lds[1024];
    const int t = threadIdx.x;
    const int CH = (N_NODES + 1023) / 1024;  // 98
    int base = t * CH;
    int end = base + CH; if (end > N_NODES) end = N_NODES;
    int s = 0;
    for (int i = base; i < end; i++) s += cnt[i];
    lds[t] = s;
    __syncthreads();
    for (int off = 1; off < 1024; off <<= 1) {
        int v = (t >= off) ? lds[t - off] : 0;
        __syncthreads();
        lds[t] += v;
        __syncthreads();
    }
    int run = lds[t] - s;
    for (int i = base; i < end; i++) {
        ofs[i] = run;
        run += cnt[i];
    }
    if (t == 1023) ofs[N_NODES] = lds[1023];  // == E
}

// ---------------- fused: degree chain-walk + layer-1 GEMM (2-node), fp8 out ----------------
__global__ __launch_bounds__(256) void k_gemm1_deg(const float* __restrict__ x,
                                                   const float* __restrict__ W1,
                                                   const int* __restrict__ head,
                                                   const int2* __restrict__ node2,
                                                   int* __restrict__ cnt,
                                                   float* __restrict__ dinv,
                                                   unsigned char* __restrict__ y1q) {
    __shared__ float w[F_IN][H1];  // 64 KB
    {
        const float4* Wv = (const float4*)W1;
        float4* wv = (float4*)&w[0][0];
        for (int i = threadIdx.x; i < F_IN * H1 / 4; i += 256) wv[i] = Wv[i];
    }

    int n0 = blockIdx.x * 512 + threadIdx.x;
    int n1 = n0 + 256;
    bool v0 = n0 < N_NODES, v1 = n1 < N_NODES;
    int n0c = v0 ? n0 : 0, n1c = v1 ? n1 : 0;

    // ---- degree walk (2 chains, ILP) ----
    int e0 = v0 ? head[n0] : -1;
    int e1 = v1 ? head[n1] : -1;
    int k0 = 0, k1 = 0;
    while (e0 >= 0 && e1 >= 0) {
        int t0 = node2[e0].y, t1 = node2[e1].y;
        k0++; k1++;
        e0 = t0; e1 = t1;
    }
    while (e0 >= 0) { k0++; e0 = node2[e0].y; }
    while (e1 >= 0) { k1++; e1 = node2[e1].y; }
    float dv0 = rsqrtf(1.0f + (float)k0);
    float dv1 = rsqrtf(1.0f + (float)k1);
    if (v0) { cnt[n0] = k0; dinv[n0] = dv0; }
    if (v1) { cnt[n1] = k1; dinv[n1] = dv1; }

    __syncthreads();  // W1 staged

    float acc0[H1], acc1[H1];
#pragma unroll
    for (int j = 0; j < H1; j++) { acc0[j] = 0.0f; acc1[j] = 0.0f; }

    const float4* xr0 = (const float4*)(x + (size_t)n0c * F_IN);
    const float4* xr1 = (const float4*)(x + (size_t)n1c * F_IN);
#pragma unroll 2
    for (int kk = 0; kk < F_IN / 4; kk++) {
        float4 xa = xr0[kk];
        float4 xb = xr1[kk];
#pragma unroll
        for (int d = 0; d < 4; d++) {
            float xv0 = (d == 0 ? xa.x : d == 1 ? xa.y : d == 2 ? xa.z : xa.w);
            float xv1 = (d == 0 ? xb.x : d == 1 ? xb.y : d == 2 ? xb.z : xb.w);
            const float4* wr = (const float4*)&w[kk * 4 + d][0];
#pragma unroll
            for (int j4 = 0; j4 < H1 / 4; j4++) {
                float4 wq = wr[j4];
                acc0[j4 * 4 + 0] += xv0 * wq.x;
                acc0[j4 * 4 + 1] += xv0 * wq.y;
                acc0[j4 * 4 + 2] += xv0 * wq.z;
                acc0[j4 * 4 + 3] += xv0 * wq.w;
                acc1[j4 * 4 + 0] += xv1 * wq.x;
                acc1[j4 * 4 + 1] += xv1 * wq.y;
                acc1[j4 * 4 + 2] += xv1 * wq.z;
                acc1[j4 * 4 + 3] += xv1 * wq.w;
            }
        }
    }
    if (v0) {
        unsigned pk[H1 / 4];
#pragma unroll
        for (int q = 0; q < H1 / 4; q++) {
            unsigned b0 = f2fp8(acc0[4 * q + 0] * dv0);
            unsigned b1 = f2fp8(acc0[4 * q + 1] * dv0);
            unsigned b2 = f2fp8(acc0[4 * q + 2] * dv0);
            unsigned b3 = f2fp8(acc0[4 * q + 3] * dv0);
            pk[q] = b0 | (b1 << 8) | (b2 << 16) | (b3 << 24);
        }
        uint4* o = (uint4*)(y1q + (size_t)n0 * H1);
#pragma unroll
        for (int q = 0; q < H1 / 16; q++)
            o[q] = make_uint4(pk[q * 4], pk[q * 4 + 1], pk[q * 4 + 2], pk[q * 4 + 3]);
    }
    if (v1) {
        unsigned pk[H1 / 4];
#pragma unroll
        for (int q = 0; q < H1 / 4; q++) {
            unsigned b0 = f2fp8(acc1[4 * q + 0] * dv1);
            unsigned b1 = f2fp8(acc1[4 * q + 1] * dv1);
            unsigned b2 = f2fp8(acc1[4 * q + 2] * dv1);
            unsigned b3 = f2fp8(acc1[4 * q + 3] * dv1);
            pk[q] = b0 | (b1 << 8) | (b2 << 16) | (b3 << 24);
        }
        uint4* o = (uint4*)(y1q + (size_t)n1 * H1);
#pragma unroll
        for (int q = 0; q < H1 / 16; q++)
            o[q] = make_uint4(pk[q * 4], pk[q * 4 + 1], pk[q * 4 + 2], pk[q * 4 + 3]);
    }
}

// ---------------- fused: chain-gather layer1 (fp8 ALU-dec) + CSR write + ReLU + GEMM2 -> y2 (fp8) ----------------
// block=256 = 4 waves; wave walks TWO chains; lanes 0/1 record srcs into CSR.
__global__ __launch_bounds__(256) void k_agg1_gemm2(const unsigned char* __restrict__ y1q,
                                                    const int* __restrict__ head,
                                                    const int2* __restrict__ node2,
                                                    const int* __restrict__ ofs,
                                                    int* __restrict__ csr,
                                                    const float* __restrict__ dinv,
                                                    const float* __restrict__ b1,
                                                    const float* __restrict__ W2,
                                                    unsigned char* __restrict__ y2q) {
    __shared__ float w2s[H1][H2];  // 8 KB
    __shared__ float hbuf[8][H1];  // 2 KB
    const int t = threadIdx.x;
    {
        const float4* Wv = (const float4*)W2;
        float4* wv = (float4*)&w2s[0][0];
        for (int i = t; i < H1 * H2 / 4; i += 256) wv[i] = Wv[i];
    }
    __syncthreads();

    const int wid = t >> 6;
    const int lane = t & 63;
    const int c = lane;
    const int n0 = blockIdx.x * 8 + wid * 2;
    const int n1 = n0 + 1;

    float a0 = fp8dec(y1q[(size_t)n0 * H1 + c]);  // self-loop
    float a1 = fp8dec(y1q[(size_t)n1 * H1 + c]);
    int e0 = head[n0], e1 = head[n1];
    const int ofs0 = ofs[n0], ofs1 = ofs[n1];
    int k = 0;
    while (e0 >= 0 && e1 >= 0) {
        int2 v0 = node2[e0];
        int2 v1 = node2[e1];
        if (lane == 0) csr[ofs0 + k] = v0.x;
        if (lane == 1) csr[ofs1 + k] = v1.x;
        a0 += fp8dec(y1q[(size_t)v0.x * H1 + c]);
        a1 += fp8dec(y1q[(size_t)v1.x * H1 + c]);
        e0 = v0.y; e1 = v1.y; k++;
    }
    int k0 = k, k1 = k;
    while (e0 >= 0) {
        int2 v0 = node2[e0];
        if (lane == 0) csr[ofs0 + k0] = v0.x;
        a0 += fp8dec(y1q[(size_t)v0.x * H1 + c]);
        e0 = v0.y; k0++;
    }
    while (e1 >= 0) {
        int2 v1 = node2[e1];
        if (lane == 1) csr[ofs1 + k1] = v1.x;
        a1 += fp8dec(y1q[(size_t)v1.x * H1 + c]);
        e1 = v1.y; k1++;
    }
    float h0 = dinv[n0] * a0 + b1[c];
    float h1v = dinv[n1] * a1 + b1[c];
    hbuf[wid * 2 + 0][c] = h0 > 0.0f ? h0 : 0.0f;
    hbuf[wid * 2 + 1][c] = h1v > 0.0f ? h1v : 0.0f;
    __syncthreads();

    // GEMM2: 256 threads = 8 nodes x 32 outputs -> fp8 store
    {
        int w = t >> 5, j = t & 31;
        int n2 = blockIdx.x * 8 + w;
        float dot = 0.0f;
#pragma unroll
        for (int cc = 0; cc < H1; cc++) dot += hbuf[w][cc] * w2s[cc][j];
        y2q[(size_t)n2 * H2 + j] = f2fp8(dinv[n2] * dot);
    }
}

// ---------------- CSR-gather layer2 (fp8 ALU-dec) + ReLU + mean-pool ----------------
// block=256 = 8 half-waves = 8 nodes; index reads are sequential broadcasts.
__global__ __launch_bounds__(256) void k_agg2_pool(const unsigned char* __restrict__ y2q,
                                                   const int* __restrict__ ofs,
                                                   const int* __restrict__ csr,
                                                   const float* __restrict__ dinv,
                                                   const float* __restrict__ b2,
                                                   float* __restrict__ g) {
    __shared__ float red[256];
    const int t = threadIdx.x;
    const int n = blockIdx.x * 8 + (t >> 5);
    const int c = t & 31;

    float a = fp8dec(y2q[(size_t)n * H2 + c]);  // self-loop
    const int p0 = ofs[n], p1 = ofs[n + 1];
    for (int p = p0; p < p1; p++) {
        int s = csr[p];
        a += fp8dec(y2q[(size_t)s * H2 + c]);
    }
    float hv = dinv[n] * a + b2[c];
    red[t] = hv > 0.0f ? hv : 0.0f;
    __syncthreads();
    if (t < 128) red[t] += red[t + 128];
    __syncthreads();
    if (t < 64) red[t] += red[t + 64];
    __syncthreads();
    if (t < 32) {
        float s = red[t] + red[t + 32];
        atomicAdd(&g[t], s);
    }
}

__global__ void k_fc(const float* __restrict__ g, const float* __restrict__ Wfc,
                     const float* __restrict__ bfc, float* __restrict__ out) {
    int c = blockIdx.x * 256 + threadIdx.x;
    if (c < C_OUT) {
        const float invn = 1.0f / (float)N_NODES;
        float s = bfc[c];
#pragma unroll
        for (int k = 0; k < H2; k++) s += (g[k] * invn) * Wfc[k * C_OUT + c];
        out[c] = s;
    }
}

extern "C" void kernel_launch(void* const* d_in, const int* in_sizes, int n_in,
                              void* d_out, int out_size, void* d_ws, size_t ws_size,
                              hipStream_t stream) {
    const float* x   = (const float*)d_in[0];
    const int* esrc  = (const int*)d_in[1];
    const int* edst  = (const int*)d_in[2];
    const float* W1  = (const float*)d_in[3];
    const float* b1  = (const float*)d_in[4];
    const float* W2  = (const float*)d_in[5];
    const float* b2  = (const float*)d_in[6];
    const float* Wfc = (const float*)d_in[7];
    const float* bfc = (const float*)d_in[8];
    float* out = (float*)d_out;

    float* ws = (float*)d_ws;
    float* g    = ws + OFF_G;
    float* dinv = ws + OFF_DINV;
    int*   cnt  = (int*)(ws + OFF_CNT);
    int*   head = (int*)(ws + OFF_HEAD);
    int*   ofs  = (int*)(ws + OFF_OFS);
    int*   csr  = (int*)(ws + OFF_CSR);
    int2*  node2 = (int2*)(ws + OFF_NODE2);
    unsigned char* y1q = (unsigned char*)(ws + OFF_Y1Q);
    unsigned char* y2q = (unsigned char*)(ws + OFF_Y2Q);

    const int nb_n = (N_NODES + 255) / 256;  // 391
    const int nb_e = (N_EDGES + 255) / 256;  // 12500

    k_init<<<nb_n, 256, 0, stream>>>(head, g);
    k_build<<<nb_e, 256, 0, stream>>>(esrc, edst, head, node2);

    k_gemm1_deg<<<(N_NODES + 511) / 512, 256, 0, stream>>>(x, W1, head, node2, cnt, dinv, y1q);
    k_scan<<<1, 1024, 0, stream>>>(cnt, ofs);

    k_agg1_gemm2<<<N_NODES / 8, 256, 0, stream>>>(y1q, head, node2, ofs, csr, dinv, b1, W2, y2q);
    k_agg2_pool<<<N_NODES / 8, 256, 0, stream>>>(y2q, ofs, csr, dinv, b2, g);

    k_fc<<<(C_OUT + 255) / 256, 256, 0, stream>>>(g, Wfc, bfc, out);
}